// Round 6
// baseline (3197.331 us; speedup 1.0000x reference)
//
#include <hip/hip_runtime.h>
#include <hip/hip_bf16.h>

#define DIM 128

typedef unsigned short u16;
typedef unsigned int u32;

__device__ __forceinline__ float bf2f(u16 u) {
    union { unsigned int i; float f; } v;
    v.i = ((unsigned int)u) << 16;
    return v.f;
}

__device__ __forceinline__ u16 f2bf(float f) {
    union { float f; unsigned int i; } v;
    v.f = f;
    unsigned int x = v.i;
    return (u16)((x + 0x7fffu + ((x >> 16) & 1u)) >> 16);
}

// ---------------- zero-fill ints --------------------------------------------
__global__ __launch_bounds__(256) void zeroi_kernel(int* __restrict__ p, int n)
{
    int i = blockIdx.x * 256 + threadIdx.x;
    if (i < n) p[i] = 0;
}

// ---------------- CSR build: histogram (int atomics, device-scope) ----------
__global__ __launch_bounds__(256) void hist_kernel(const int* __restrict__ dst, int E,
                                                   int* __restrict__ deg)
{
    int e = blockIdx.x * 256 + threadIdx.x;
    if (e < E) atomicAdd(&deg[dst[e]], 1);
}

// ---------------- exclusive scan, single block of 1024 ----------------------
__global__ __launch_bounds__(1024) void scan_kernel(const int* __restrict__ deg,
                                                    int* __restrict__ rowptr, int N)
{
    __shared__ int ps[1024];
    const int t = threadIdx.x;
    const int chunk = (N + 1023) >> 10;
    int lo = t * chunk;
    int hi = lo + chunk; if (hi > N) hi = N;
    if (lo > N) lo = N;
    int s = 0;
    for (int i = lo; i < hi; ++i) s += deg[i];
    ps[t] = s;
    __syncthreads();
    for (int o = 1; o < 1024; o <<= 1) {
        int v = (t >= o) ? ps[t - o] : 0;
        __syncthreads();
        ps[t] += v;
        __syncthreads();
    }
    int base = (t == 0) ? 0 : ps[t - 1];
    for (int i = lo; i < hi; ++i) { rowptr[i] = base; base += deg[i]; }
    if (t == 1023) rowptr[N] = ps[1023];
}

// ---------------- CSR fill (int atomics for slot assignment) ----------------
__global__ __launch_bounds__(256) void fill_kernel(const int* __restrict__ src,
                                                   const int* __restrict__ dst, int E,
                                                   const int* __restrict__ rowptr,
                                                   int* __restrict__ cur,
                                                   int* __restrict__ elist)
{
    int e = blockIdx.x * 256 + threadIdx.x;
    if (e >= E) return;
    int d = dst[e];
    int pos = atomicAdd(&cur[d], 1);
    elist[rowptr[d] + pos] = src[e];
}

// ---------------- gather-side mean (deterministic, no atomics) --------------
// 32 lanes per node, 4 features/lane; fp32 accumulate; bf16 out (meanA).
__global__ __launch_bounds__(256) void gather_mean_kernel(
    const float* __restrict__ feat,
    const int* __restrict__ elist, const int* __restrict__ rowptr,
    int N, u16* __restrict__ meanA)
{
    int node = blockIdx.x * 8 + (threadIdx.x >> 5);
    int lane = threadIdx.x & 31;
    if (node >= N) return;
    int r0 = rowptr[node], r1 = rowptr[node + 1];
    float a0 = 0.f, a1 = 0.f, a2 = 0.f, a3 = 0.f;
    for (int j = r0; j < r1; ++j) {
        int s = elist[j];
        float4 x = *(const float4*)(feat + (size_t)s * DIM + lane * 4);
        a0 += x.x; a1 += x.y; a2 += x.z; a3 += x.w;
    }
    float sc = (r1 > r0) ? (1.f / (float)(r1 - r0)) : 0.f;
    uint2 o;
    o.x = (u32)f2bf(a0 * sc) | ((u32)f2bf(a1 * sc) << 16);
    o.y = (u32)f2bf(a2 * sc) | ((u32)f2bf(a3 * sc) << 16);
    ((uint2*)(meanA + (size_t)node * DIM))[lane] = o;
}

// ---------------- transform (VALU f32): B[n] = deg>0 ? W*meanA[n] + b : 0 ---
// Linearity: mean(W x + b) = W mean(x) + b when deg>0; exact 0 when deg==0.
__global__ __launch_bounds__(256) void transform_gemv(
    const u16* __restrict__ meanA, const int* __restrict__ rowptr,
    const float* __restrict__ W, const float* __restrict__ bias,
    float* __restrict__ outB, int N)
{
    __shared__ float xs[2][DIM];
    const int local = threadIdx.x >> 7;       // 0,1
    const int o = threadIdx.x & 127;
    const int n = blockIdx.x * 2 + local;
    xs[local][o] = (n < N) ? bf2f(meanA[(size_t)n * DIM + o]) : 0.f;
    __syncthreads();
    if (n >= N) return;
    const float* xl = xs[local];
    const float4* wr = (const float4*)(W + (size_t)o * DIM);
    float acc = 0.f;
    #pragma unroll
    for (int k4 = 0; k4 < DIM / 4; ++k4) {
        float4 w = wr[k4];
        acc += w.x * xl[k4 * 4 + 0];
        acc += w.y * xl[k4 * 4 + 1];
        acc += w.z * xl[k4 * 4 + 2];
        acc += w.w * xl[k4 * 4 + 3];
    }
    bool has = rowptr[n + 1] > rowptr[n];
    outB[(size_t)n * DIM + o] = has ? (acc + bias[o]) : 0.f;
}

// ---------------- update (VALU f32): relu([A1[n], B[n]] @ W^T + b) ----------
// All f32. Writes up to two f32 destinations (ws intermediate and/or d_out).
__global__ __launch_bounds__(256) void update_gemv(
    const float* __restrict__ A1, const float* __restrict__ B,
    const float* __restrict__ W, const float* __restrict__ bias,
    float* __restrict__ outC, float* __restrict__ outF, int N)
{
    __shared__ float xs[2][2 * DIM];
    const int local = threadIdx.x >> 7;
    const int o = threadIdx.x & 127;
    const int n = blockIdx.x * 2 + local;
    if (n < N) {
        xs[local][o] = A1[(size_t)n * DIM + o];
        xs[local][DIM + o] = B[(size_t)n * DIM + o];
    }
    __syncthreads();
    if (n >= N) return;
    const float* xl = xs[local];
    const float4* wr = (const float4*)(W + (size_t)o * (2 * DIM));
    float acc = bias[o];
    #pragma unroll
    for (int k4 = 0; k4 < (2 * DIM) / 4; ++k4) {
        float4 w = wr[k4];
        acc += w.x * xl[k4 * 4 + 0];
        acc += w.y * xl[k4 * 4 + 1];
        acc += w.z * xl[k4 * 4 + 2];
        acc += w.w * xl[k4 * 4 + 3];
    }
    acc = acc > 0.f ? acc : 0.f;
    if (outC) outC[(size_t)n * DIM + o] = acc;
    if (outF) outF[(size_t)n * DIM + o] = acc;
}

extern "C" void kernel_launch(void* const* d_in, const int* in_sizes, int n_in,
                              void* d_out, int out_size, void* d_ws, size_t ws_size,
                              hipStream_t stream)
{
    const float* tile_h   = (const float*)d_in[0];
    const float* piece_h  = (const float*)d_in[1];
    const int* tile_src   = (const int*)d_in[2];
    const int* piece_dst  = (const int*)d_in[3];
    const int* piece_src  = (const int*)d_in[4];
    const int* tile_dst   = (const int*)d_in[5];
    const int* t_src      = (const int*)d_in[6];
    const int* t_dst      = (const int*)d_in[7];
    const float* W_t2p = (const float*)d_in[8];
    const float* b_t2p = (const float*)d_in[9];
    const float* W_pu  = (const float*)d_in[10];
    const float* b_pu  = (const float*)d_in[11];
    const float* W_p2t = (const float*)d_in[12];
    const float* b_p2t = (const float*)d_in[13];
    const float* W_tup = (const float*)d_in[14];
    const float* b_tup = (const float*)d_in[15];
    const float* W_t2t = (const float*)d_in[16];
    const float* b_t2t = (const float*)d_in[17];
    const float* W_tut = (const float*)d_in[18];
    const float* b_tut = (const float*)d_in[19];

    const int NT  = in_sizes[0] / DIM;   // 50000
    const int NP  = in_sizes[1] / DIM;   // 25000
    const int EPT = in_sizes[2];         // 400000
    const int ETT = in_sizes[6];         // 600000
    const int EMX = (EPT > ETT) ? EPT : ETT;

    // ---- workspace layout (~66 MB) ----
    char* ws = (char*)d_ws;
    size_t off = 0;
    int* deg = (int*)(ws + off);     off += (size_t)NT * sizeof(int);
    int* cur = (int*)(ws + off);     off += (size_t)NT * sizeof(int);
    off = (off + 255) & ~(size_t)255;
    int* rowptr = (int*)(ws + off);  off += (size_t)(NT + 1) * sizeof(int);
    off = (off + 255) & ~(size_t)255;
    int* elist = (int*)(ws + off);   off += (size_t)EMX * sizeof(int);
    off = (off + 255) & ~(size_t)255;
    u16* A = (u16*)(ws + off);       off += (size_t)NT * DIM * sizeof(u16);   // meanA bf16
    off = (off + 255) & ~(size_t)255;
    float* B = (float*)(ws + off);   off += (size_t)NT * DIM * sizeof(float); // transform out
    off = (off + 255) & ~(size_t)255;
    float* C = (float*)(ws + off);   off += (size_t)NT * DIM * sizeof(float); // tile-mid

    float* out_tile  = (float*)d_out;                       // f32 output!
    float* out_piece = out_tile + (size_t)NT * DIM;

    dim3 blk(256);
    dim3 g_zd((unsigned)((2 * NT + 255) / 256));
    dim3 g_e1((unsigned)((EPT + 255) / 256));
    dim3 g_e3((unsigned)((ETT + 255) / 256));
    dim3 g_gp((unsigned)((NP + 7) / 8));
    dim3 g_gt((unsigned)((NT + 7) / 8));
    dim3 g_np((unsigned)((NP + 1) / 2));
    dim3 g_nt((unsigned)((NT + 1) / 2));

    // ---- Stage 1: tile -> piece ----
    hipLaunchKernelGGL(zeroi_kernel, g_zd, blk, 0, stream, deg, 2 * NT);  // deg+cur
    hipLaunchKernelGGL(hist_kernel, g_e1, blk, 0, stream, piece_dst, EPT, deg);
    hipLaunchKernelGGL(scan_kernel, dim3(1), dim3(1024), 0, stream, deg, rowptr, NP);
    hipLaunchKernelGGL(fill_kernel, g_e1, blk, 0, stream,
                       tile_src, piece_dst, EPT, rowptr, cur, elist);
    hipLaunchKernelGGL(gather_mean_kernel, g_gp, blk, 0, stream,
                       tile_h, elist, rowptr, NP, A);
    hipLaunchKernelGGL(transform_gemv, g_np, blk, 0, stream,
                       A, rowptr, W_t2p, b_t2p, B, NP);
    hipLaunchKernelGGL(update_gemv, g_np, blk, 0, stream,
                       piece_h, B, W_pu, b_pu, (float*)nullptr, out_piece, NP);

    // ---- Stage 2: piece -> tile (gather reads out_piece written above) ----
    hipLaunchKernelGGL(zeroi_kernel, g_zd, blk, 0, stream, deg, 2 * NT);
    hipLaunchKernelGGL(hist_kernel, g_e1, blk, 0, stream, tile_dst, EPT, deg);
    hipLaunchKernelGGL(scan_kernel, dim3(1), dim3(1024), 0, stream, deg, rowptr, NT);
    hipLaunchKernelGGL(fill_kernel, g_e1, blk, 0, stream,
                       piece_src, tile_dst, EPT, rowptr, cur, elist);
    hipLaunchKernelGGL(gather_mean_kernel, g_gt, blk, 0, stream,
                       out_piece, elist, rowptr, NT, A);
    hipLaunchKernelGGL(transform_gemv, g_nt, blk, 0, stream,
                       A, rowptr, W_p2t, b_p2t, B, NT);
    hipLaunchKernelGGL(update_gemv, g_nt, blk, 0, stream,
                       tile_h, B, W_tup, b_tup, C, (float*)nullptr, NT);

    // ---- Stage 3: tile -> tile ----
    hipLaunchKernelGGL(zeroi_kernel, g_zd, blk, 0, stream, deg, 2 * NT);
    hipLaunchKernelGGL(hist_kernel, g_e3, blk, 0, stream, t_dst, ETT, deg);
    hipLaunchKernelGGL(scan_kernel, dim3(1), dim3(1024), 0, stream, deg, rowptr, NT);
    hipLaunchKernelGGL(fill_kernel, g_e3, blk, 0, stream,
                       t_src, t_dst, ETT, rowptr, cur, elist);
    hipLaunchKernelGGL(gather_mean_kernel, g_gt, blk, 0, stream,
                       C, elist, rowptr, NT, A);
    hipLaunchKernelGGL(transform_gemv, g_nt, blk, 0, stream,
                       A, rowptr, W_t2t, b_t2t, B, NT);
    hipLaunchKernelGGL(update_gemv, g_nt, blk, 0, stream,
                       C, B, W_tut, b_tut, (float*)nullptr, out_tile, NT);
}

// Round 7
// 641.891 us; speedup vs baseline: 4.9811x; 4.9811x over previous
//
#include <hip/hip_runtime.h>
#include <hip/hip_bf16.h>

#define DIM 128

typedef unsigned short u16;
typedef unsigned int u32;
typedef __attribute__((ext_vector_type(8))) short v8s;
typedef __attribute__((ext_vector_type(4))) float v4f;

__device__ __forceinline__ float bf2f(u16 u) {
    union { unsigned int i; float f; } v;
    v.i = ((unsigned int)u) << 16;
    return v.f;
}

__device__ __forceinline__ u16 f2bf(float f) {
    union { float f; unsigned int i; } v;
    v.f = f;
    unsigned int x = v.i;
    return (u16)((x + 0x7fffu + ((x >> 16) & 1u)) >> 16);
}

// ---------------- zero-fill ints --------------------------------------------
__global__ __launch_bounds__(256) void zeroi_kernel(int* __restrict__ p, int n)
{
    int i = blockIdx.x * 256 + threadIdx.x;
    if (i < n) p[i] = 0;
}

// ---------------- CSR build: histogram --------------------------------------
__global__ __launch_bounds__(256) void hist_kernel(const int* __restrict__ dst, int E,
                                                   int* __restrict__ deg)
{
    int e = blockIdx.x * 256 + threadIdx.x;
    if (e < E) atomicAdd(&deg[dst[e]], 1);
}

// ---------------- exclusive scan, single block of 1024 ----------------------
__global__ __launch_bounds__(1024) void scan_kernel(const int* __restrict__ deg,
                                                    int* __restrict__ rowptr, int N)
{
    __shared__ int ps[1024];
    const int t = threadIdx.x;
    const int chunk = (N + 1023) >> 10;
    int lo = t * chunk;
    int hi = lo + chunk; if (hi > N) hi = N;
    if (lo > N) lo = N;
    int s = 0;
    for (int i = lo; i < hi; ++i) s += deg[i];
    ps[t] = s;
    __syncthreads();
    for (int o = 1; o < 1024; o <<= 1) {
        int v = (t >= o) ? ps[t - o] : 0;
        __syncthreads();
        ps[t] += v;
        __syncthreads();
    }
    int base = (t == 0) ? 0 : ps[t - 1];
    for (int i = lo; i < hi; ++i) { rowptr[i] = base; base += deg[i]; }
    if (t == 1023) rowptr[N] = ps[1023];
}

// ---------------- CSR fill --------------------------------------------------
__global__ __launch_bounds__(256) void fill_kernel(const int* __restrict__ src,
                                                   const int* __restrict__ dst, int E,
                                                   const int* __restrict__ rowptr,
                                                   int* __restrict__ cur,
                                                   int* __restrict__ elist)
{
    int e = blockIdx.x * 256 + threadIdx.x;
    if (e >= E) return;
    int d = dst[e];
    int pos = atomicAdd(&cur[d], 1);
    elist[rowptr[d] + pos] = src[e];
}

// ---------------- gather-side mean (deterministic) --------------------------
// 32 lanes per node, 4 features/lane; fp32 accumulate; bf16 out (meanA).
__global__ __launch_bounds__(256) void gather_mean_kernel(
    const void* __restrict__ feat, int is_f32,
    const int* __restrict__ elist, const int* __restrict__ rowptr,
    int N, u16* __restrict__ meanA)
{
    int node = blockIdx.x * 8 + (threadIdx.x >> 5);
    int lane = threadIdx.x & 31;
    if (node >= N) return;
    int r0 = rowptr[node], r1 = rowptr[node + 1];
    float a0 = 0.f, a1 = 0.f, a2 = 0.f, a3 = 0.f;
    if (is_f32) {
        const float* f = (const float*)feat;
        for (int j = r0; j < r1; ++j) {
            int s = elist[j];
            float4 x = *(const float4*)(f + (size_t)s * DIM + lane * 4);
            a0 += x.x; a1 += x.y; a2 += x.z; a3 += x.w;
        }
    } else {
        const u16* f = (const u16*)feat;
        for (int j = r0; j < r1; ++j) {
            int s = elist[j];
            uint2 v = ((const uint2*)(f + (size_t)s * DIM))[lane];
            a0 += bf2f((u16)(v.x & 0xffffu)); a1 += bf2f((u16)(v.x >> 16));
            a2 += bf2f((u16)(v.y & 0xffffu)); a3 += bf2f((u16)(v.y >> 16));
        }
    }
    float sc = (r1 > r0) ? (1.f / (float)(r1 - r0)) : 0.f;
    uint2 o;
    o.x = (u32)f2bf(a0 * sc) | ((u32)f2bf(a1 * sc) << 16);
    o.y = (u32)f2bf(a2 * sc) | ((u32)f2bf(a3 * sc) << 16);
    ((uint2*)(meanA + (size_t)node * DIM))[lane] = o;
}

// ---------------- transform (MFMA): B[n] = deg>0 ? W*meanA[n] + b : 0 -------
// 64-node tile/block, W [128][128] f32 -> LDS bf16. Output bf16.
__global__ __launch_bounds__(256) void transform_mfma(
    const u16* __restrict__ meanA, const int* __restrict__ rowptr,
    const float* __restrict__ W, const float* __restrict__ bias,
    u16* __restrict__ out, int N)
{
    __shared__ u16 Wl[128][136];
    __shared__ u16 Al[64][136];
    const int tid = threadIdx.x;
    const int nb = blockIdx.x * 64;

    #pragma unroll
    for (int i = 0; i < 8; ++i) {
        int c = i * 256 + tid;              // [0,2048): 8 floats each
        int row = c >> 4;
        int c8 = (c & 15) * 8;
        const float4* wp = (const float4*)(W + row * 128 + c8);
        float4 x0 = wp[0], x1 = wp[1];
        uint4 p;
        p.x = (u32)f2bf(x0.x) | ((u32)f2bf(x0.y) << 16);
        p.y = (u32)f2bf(x0.z) | ((u32)f2bf(x0.w) << 16);
        p.z = (u32)f2bf(x1.x) | ((u32)f2bf(x1.y) << 16);
        p.w = (u32)f2bf(x1.z) | ((u32)f2bf(x1.w) << 16);
        *(uint4*)&Wl[row][c8] = p;
    }
    #pragma unroll
    for (int i = 0; i < 4; ++i) {
        int c = i * 256 + tid;              // [0,1024): 8 bf16 each
        int row = c >> 4;
        int c8 = (c & 15) * 8;
        int n = nb + row;
        uint4 v = {0u, 0u, 0u, 0u};
        if (n < N) v = *(const uint4*)(meanA + (size_t)n * DIM + c8);
        *(uint4*)&Al[row][c8] = v;
    }
    __syncthreads();

    const int wave = tid >> 6;
    const int lane = tid & 63;
    const int m = lane & 15;
    const int quad = lane >> 4;

    v4f acc[8];
    #pragma unroll
    for (int t = 0; t < 8; ++t) acc[t] = (v4f){0.f, 0.f, 0.f, 0.f};

    const int arow = wave * 16 + m;
    #pragma unroll
    for (int k0 = 0; k0 < 128; k0 += 32) {
        v8s a = *(const v8s*)&Al[arow][k0 + quad * 8];
        #pragma unroll
        for (int t = 0; t < 8; ++t) {
            v8s b = *(const v8s*)&Wl[t * 16 + m][k0 + quad * 8];
            acc[t] = __builtin_amdgcn_mfma_f32_16x16x32_bf16(a, b, acc[t], 0, 0, 0);
        }
    }

    float bv[8];
    #pragma unroll
    for (int t = 0; t < 8; ++t) bv[t] = bias[t * 16 + m];

    #pragma unroll
    for (int r = 0; r < 4; ++r) {
        int n = nb + wave * 16 + quad * 4 + r;
        if (n >= N) continue;
        bool has = rowptr[n + 1] > rowptr[n];
        #pragma unroll
        for (int t = 0; t < 8; ++t) {
            float val = has ? (acc[t][r] + bv[t]) : 0.f;
            out[(size_t)n * DIM + t * 16 + m] = f2bf(val);
        }
    }
}

// ---------------- update (MFMA): relu([A1[n], B[n]] @ W^T + b) --------------
// K=256 in two halves. A1 f32 or bf16 per flag; B bf16. Outputs: outC bf16
// (ws, feeds next gather) and/or outF f32 (d_out), both nullable.
__global__ __launch_bounds__(256) void update_mfma(
    const void* __restrict__ A1, int a1_is_f32, const u16* __restrict__ B,
    const float* __restrict__ W, const float* __restrict__ bias,
    u16* __restrict__ outC, float* __restrict__ outF, int N)
{
    __shared__ u16 Wl[128][136];
    __shared__ u16 Al[64][136];
    const int tid = threadIdx.x;
    const int nb = blockIdx.x * 64;
    const int wave = tid >> 6;
    const int lane = tid & 63;
    const int m = lane & 15;
    const int quad = lane >> 4;

    v4f acc[8];
    #pragma unroll
    for (int t = 0; t < 8; ++t) acc[t] = (v4f){0.f, 0.f, 0.f, 0.f};

    for (int half = 0; half < 2; ++half) {
        if (half) __syncthreads();
        #pragma unroll
        for (int i = 0; i < 8; ++i) {
            int c = i * 256 + tid;
            int row = c >> 4;
            int c8 = (c & 15) * 8;
            const float4* wp = (const float4*)(W + row * 256 + half * 128 + c8);
            float4 x0 = wp[0], x1 = wp[1];
            uint4 p;
            p.x = (u32)f2bf(x0.x) | ((u32)f2bf(x0.y) << 16);
            p.y = (u32)f2bf(x0.z) | ((u32)f2bf(x0.w) << 16);
            p.z = (u32)f2bf(x1.x) | ((u32)f2bf(x1.y) << 16);
            p.w = (u32)f2bf(x1.z) | ((u32)f2bf(x1.w) << 16);
            *(uint4*)&Wl[row][c8] = p;
        }
        #pragma unroll
        for (int i = 0; i < 4; ++i) {
            int c = i * 256 + tid;
            int row = c >> 4;
            int c8 = (c & 15) * 8;
            int n = nb + row;
            uint4 v = {0u, 0u, 0u, 0u};
            if (n < N) {
                if (half == 0) {
                    if (a1_is_f32) {
                        const float4* ap = (const float4*)((const float*)A1 + (size_t)n * DIM + c8);
                        float4 x0 = ap[0], x1 = ap[1];
                        v.x = (u32)f2bf(x0.x) | ((u32)f2bf(x0.y) << 16);
                        v.y = (u32)f2bf(x0.z) | ((u32)f2bf(x0.w) << 16);
                        v.z = (u32)f2bf(x1.x) | ((u32)f2bf(x1.y) << 16);
                        v.w = (u32)f2bf(x1.z) | ((u32)f2bf(x1.w) << 16);
                    } else {
                        v = *(const uint4*)((const u16*)A1 + (size_t)n * DIM + c8);
                    }
                } else {
                    v = *(const uint4*)(B + (size_t)n * DIM + c8);
                }
            }
            *(uint4*)&Al[row][c8] = v;
        }
        __syncthreads();

        const int arow = wave * 16 + m;
        #pragma unroll
        for (int k0 = 0; k0 < 128; k0 += 32) {
            v8s a = *(const v8s*)&Al[arow][k0 + quad * 8];
            #pragma unroll
            for (int t = 0; t < 8; ++t) {
                v8s b = *(const v8s*)&Wl[t * 16 + m][k0 + quad * 8];
                acc[t] = __builtin_amdgcn_mfma_f32_16x16x32_bf16(a, b, acc[t], 0, 0, 0);
            }
        }
    }

    float bv[8];
    #pragma unroll
    for (int t = 0; t < 8; ++t) bv[t] = bias[t * 16 + m];

    #pragma unroll
    for (int r = 0; r < 4; ++r) {
        int n = nb + wave * 16 + quad * 4 + r;
        if (n >= N) continue;
        #pragma unroll
        for (int t = 0; t < 8; ++t) {
            float val = acc[t][r] + bv[t];
            val = val > 0.f ? val : 0.f;
            if (outC) outC[(size_t)n * DIM + t * 16 + m] = f2bf(val);
            if (outF) outF[(size_t)n * DIM + t * 16 + m] = val;
        }
    }
}

extern "C" void kernel_launch(void* const* d_in, const int* in_sizes, int n_in,
                              void* d_out, int out_size, void* d_ws, size_t ws_size,
                              hipStream_t stream)
{
    const float* tile_h   = (const float*)d_in[0];
    const float* piece_h  = (const float*)d_in[1];
    const int* tile_src   = (const int*)d_in[2];
    const int* piece_dst  = (const int*)d_in[3];
    const int* piece_src  = (const int*)d_in[4];
    const int* tile_dst   = (const int*)d_in[5];
    const int* t_src      = (const int*)d_in[6];
    const int* t_dst      = (const int*)d_in[7];
    const float* W_t2p = (const float*)d_in[8];
    const float* b_t2p = (const float*)d_in[9];
    const float* W_pu  = (const float*)d_in[10];
    const float* b_pu  = (const float*)d_in[11];
    const float* W_p2t = (const float*)d_in[12];
    const float* b_p2t = (const float*)d_in[13];
    const float* W_tup = (const float*)d_in[14];
    const float* b_tup = (const float*)d_in[15];
    const float* W_t2t = (const float*)d_in[16];
    const float* b_t2t = (const float*)d_in[17];
    const float* W_tut = (const float*)d_in[18];
    const float* b_tut = (const float*)d_in[19];

    const int NT  = in_sizes[0] / DIM;   // 50000
    const int NP  = in_sizes[1] / DIM;   // 25000
    const int EPT = in_sizes[2];         // 400000
    const int ETT = in_sizes[6];         // 600000
    const int EMX = (EPT > ETT) ? EPT : ETT;

    // ---- workspace layout (~42 MB) ----
    char* ws = (char*)d_ws;
    size_t off = 0;
    int* deg = (int*)(ws + off);     off += (size_t)NT * sizeof(int);
    int* cur = (int*)(ws + off);     off += (size_t)NT * sizeof(int);
    off = (off + 255) & ~(size_t)255;
    int* rowptr = (int*)(ws + off);  off += (size_t)(NT + 1) * sizeof(int);
    off = (off + 255) & ~(size_t)255;
    int* elist = (int*)(ws + off);   off += (size_t)EMX * sizeof(int);
    off = (off + 255) & ~(size_t)255;
    u16* A = (u16*)(ws + off);       off += (size_t)NT * DIM * sizeof(u16);   // meanA bf16
    off = (off + 255) & ~(size_t)255;
    u16* B = (u16*)(ws + off);       off += (size_t)NT * DIM * sizeof(u16);   // transform out bf16
    off = (off + 255) & ~(size_t)255;
    u16* C = (u16*)(ws + off);       off += (size_t)NT * DIM * sizeof(u16);   // node-mid bf16

    float* out_tile  = (float*)d_out;
    float* out_piece = out_tile + (size_t)NT * DIM;

    dim3 blk(256);
    dim3 g_zd((unsigned)((2 * NT + 255) / 256));
    dim3 g_e1((unsigned)((EPT + 255) / 256));
    dim3 g_e3((unsigned)((ETT + 255) / 256));
    dim3 g_gp((unsigned)((NP + 7) / 8));
    dim3 g_gt((unsigned)((NT + 7) / 8));
    dim3 g_np((unsigned)((NP + 63) / 64));
    dim3 g_nt((unsigned)((NT + 63) / 64));

    // ---- Stage 1: tile -> piece ----
    hipLaunchKernelGGL(zeroi_kernel, g_zd, blk, 0, stream, deg, 2 * NT);
    hipLaunchKernelGGL(hist_kernel, g_e1, blk, 0, stream, piece_dst, EPT, deg);
    hipLaunchKernelGGL(scan_kernel, dim3(1), dim3(1024), 0, stream, deg, rowptr, NP);
    hipLaunchKernelGGL(fill_kernel, g_e1, blk, 0, stream,
                       tile_src, piece_dst, EPT, rowptr, cur, elist);
    hipLaunchKernelGGL(gather_mean_kernel, g_gp, blk, 0, stream,
                       (const void*)tile_h, 1, elist, rowptr, NP, A);
    hipLaunchKernelGGL(transform_mfma, g_np, blk, 0, stream,
                       A, rowptr, W_t2p, b_t2p, B, NP);
    hipLaunchKernelGGL(update_mfma, g_np, blk, 0, stream,
                       (const void*)piece_h, 1, B, W_pu, b_pu, C, out_piece, NP);

    // ---- Stage 2: piece -> tile (gather reads bf16 C = piece feats) ----
    hipLaunchKernelGGL(zeroi_kernel, g_zd, blk, 0, stream, deg, 2 * NT);
    hipLaunchKernelGGL(hist_kernel, g_e1, blk, 0, stream, tile_dst, EPT, deg);
    hipLaunchKernelGGL(scan_kernel, dim3(1), dim3(1024), 0, stream, deg, rowptr, NT);
    hipLaunchKernelGGL(fill_kernel, g_e1, blk, 0, stream,
                       piece_src, tile_dst, EPT, rowptr, cur, elist);
    hipLaunchKernelGGL(gather_mean_kernel, g_gt, blk, 0, stream,
                       (const void*)C, 0, elist, rowptr, NT, A);
    hipLaunchKernelGGL(transform_mfma, g_nt, blk, 0, stream,
                       A, rowptr, W_p2t, b_p2t, B, NT);
    hipLaunchKernelGGL(update_mfma, g_nt, blk, 0, stream,
                       (const void*)tile_h, 1, B, W_tup, b_tup, C, (float*)nullptr, NT);

    // ---- Stage 3: tile -> tile (gather reads bf16 C = tile-mid) ----
    hipLaunchKernelGGL(zeroi_kernel, g_zd, blk, 0, stream, deg, 2 * NT);
    hipLaunchKernelGGL(hist_kernel, g_e3, blk, 0, stream, t_dst, ETT, deg);
    hipLaunchKernelGGL(scan_kernel, dim3(1), dim3(1024), 0, stream, deg, rowptr, NT);
    hipLaunchKernelGGL(fill_kernel, g_e3, blk, 0, stream,
                       t_src, t_dst, ETT, rowptr, cur, elist);
    hipLaunchKernelGGL(gather_mean_kernel, g_gt, blk, 0, stream,
                       (const void*)C, 0, elist, rowptr, NT, A);
    hipLaunchKernelGGL(transform_mfma, g_nt, blk, 0, stream,
                       A, rowptr, W_t2t, b_t2t, B, NT);
    hipLaunchKernelGGL(update_mfma, g_nt, blk, 0, stream,
                       (const void*)C, 0, B, W_tut, b_tut, (u16*)nullptr, out_tile, NT);
}

// Round 8
// 491.914 us; speedup vs baseline: 6.4998x; 1.3049x over previous
//
#include <hip/hip_runtime.h>
#include <hip/hip_bf16.h>

#define DIM 128

typedef unsigned short u16;
typedef unsigned int u32;
typedef __attribute__((ext_vector_type(8))) short v8s;
typedef __attribute__((ext_vector_type(4))) float v4f;

__device__ __forceinline__ float bf2f(u16 u) {
    union { unsigned int i; float f; } v;
    v.i = ((unsigned int)u) << 16;
    return v.f;
}

__device__ __forceinline__ u16 f2bf(float f) {
    union { float f; unsigned int i; } v;
    v.f = f;
    unsigned int x = v.i;
    return (u16)((x + 0x7fffu + ((x >> 16) & 1u)) >> 16);
}

// ---------------- zero-fill ints --------------------------------------------
__global__ __launch_bounds__(256) void zeroi_kernel(int* __restrict__ p, int n)
{
    int i = blockIdx.x * 256 + threadIdx.x;
    if (i < n) p[i] = 0;
}

// ---------------- CSR build: histogram --------------------------------------
__global__ __launch_bounds__(256) void hist_kernel(const int* __restrict__ dst, int E,
                                                   int* __restrict__ deg)
{
    int e = blockIdx.x * 256 + threadIdx.x;
    if (e < E) atomicAdd(&deg[dst[e]], 1);
}

// ---------------- two-level exclusive scan ----------------------------------
// scan_part: block b handles 2048 elems; per-element in-block exclusive prefix
// -> partial[], block total -> blocksum[b].
__global__ __launch_bounds__(256) void scan_part(const int* __restrict__ deg,
                                                 int* __restrict__ partial,
                                                 int* __restrict__ blocksum, int N)
{
    __shared__ int ls[256];
    const int base = blockIdx.x * 2048;
    const int t = threadIdx.x;
    int v[8];
    int s = 0;
    #pragma unroll
    for (int i = 0; i < 8; ++i) {
        int idx = base + t * 8 + i;
        v[i] = (idx < N) ? deg[idx] : 0;
        s += v[i];
    }
    ls[t] = s;
    __syncthreads();
    #pragma unroll
    for (int o = 1; o < 256; o <<= 1) {
        int x = (t >= o) ? ls[t - o] : 0;
        __syncthreads();
        ls[t] += x;
        __syncthreads();
    }
    int run = (t == 0) ? 0 : ls[t - 1];
    #pragma unroll
    for (int i = 0; i < 8; ++i) {
        int idx = base + t * 8 + i;
        if (idx < N) partial[idx] = run;
        run += v[i];
    }
    if (t == 255) blocksum[blockIdx.x] = ls[255];
}

// scan_fix: add block offsets -> rowptr; zero cur; set rowptr[N]=E.
__global__ __launch_bounds__(256) void scan_fix(const int* __restrict__ partial,
                                                const int* __restrict__ blocksum,
                                                int* __restrict__ rowptr,
                                                int* __restrict__ cur, int N, int E)
{
    __shared__ int off_s;
    const int base = blockIdx.x * 2048;
    const int t = threadIdx.x;
    if (t == 0) {
        int o = 0;
        for (int b = 0; b < (int)blockIdx.x; ++b) o += blocksum[b];
        off_s = o;
    }
    __syncthreads();
    const int off = off_s;
    #pragma unroll
    for (int i = 0; i < 8; ++i) {
        int idx = base + t * 8 + i;
        if (idx < N) { rowptr[idx] = partial[idx] + off; cur[idx] = 0; }
    }
    if (blockIdx.x == gridDim.x - 1 && t == 255) rowptr[N] = E;
}

// ---------------- CSR fill --------------------------------------------------
__global__ __launch_bounds__(256) void fill_kernel(const int* __restrict__ src,
                                                   const int* __restrict__ dst, int E,
                                                   const int* __restrict__ rowptr,
                                                   int* __restrict__ cur,
                                                   int* __restrict__ elist)
{
    int e = blockIdx.x * 256 + threadIdx.x;
    if (e >= E) return;
    int d = dst[e];
    int pos = atomicAdd(&cur[d], 1);
    elist[rowptr[d] + pos] = src[e];
}

// ---------------- gather-side mean (deterministic) --------------------------
__global__ __launch_bounds__(256) void gather_mean_kernel(
    const void* __restrict__ feat, int is_f32,
    const int* __restrict__ elist, const int* __restrict__ rowptr,
    int N, u16* __restrict__ meanA)
{
    int node = blockIdx.x * 8 + (threadIdx.x >> 5);
    int lane = threadIdx.x & 31;
    if (node >= N) return;
    int r0 = rowptr[node], r1 = rowptr[node + 1];
    float a0 = 0.f, a1 = 0.f, a2 = 0.f, a3 = 0.f;
    if (is_f32) {
        const float* f = (const float*)feat;
        for (int j = r0; j < r1; ++j) {
            int s = elist[j];
            float4 x = *(const float4*)(f + (size_t)s * DIM + lane * 4);
            a0 += x.x; a1 += x.y; a2 += x.z; a3 += x.w;
        }
    } else {
        const u16* f = (const u16*)feat;
        for (int j = r0; j < r1; ++j) {
            int s = elist[j];
            uint2 v = ((const uint2*)(f + (size_t)s * DIM))[lane];
            a0 += bf2f((u16)(v.x & 0xffffu)); a1 += bf2f((u16)(v.x >> 16));
            a2 += bf2f((u16)(v.y & 0xffffu)); a3 += bf2f((u16)(v.y >> 16));
        }
    }
    float sc = (r1 > r0) ? (1.f / (float)(r1 - r0)) : 0.f;
    uint2 o;
    o.x = (u32)f2bf(a0 * sc) | ((u32)f2bf(a1 * sc) << 16);
    o.y = (u32)f2bf(a2 * sc) | ((u32)f2bf(a3 * sc) << 16);
    ((uint2*)(meanA + (size_t)node * DIM))[lane] = o;
}

// ---------------- transform (MFMA): B[n] = deg>0 ? W*meanA[n] + b : 0 -------
__global__ __launch_bounds__(256) void transform_mfma(
    const u16* __restrict__ meanA, const int* __restrict__ rowptr,
    const float* __restrict__ W, const float* __restrict__ bias,
    u16* __restrict__ out, int N)
{
    __shared__ u16 Wl[128][136];
    __shared__ u16 Al[64][136];
    const int tid = threadIdx.x;
    const int nb = blockIdx.x * 64;

    #pragma unroll
    for (int i = 0; i < 8; ++i) {
        int c = i * 256 + tid;
        int row = c >> 4;
        int c8 = (c & 15) * 8;
        const float4* wp = (const float4*)(W + row * 128 + c8);
        float4 x0 = wp[0], x1 = wp[1];
        uint4 p;
        p.x = (u32)f2bf(x0.x) | ((u32)f2bf(x0.y) << 16);
        p.y = (u32)f2bf(x0.z) | ((u32)f2bf(x0.w) << 16);
        p.z = (u32)f2bf(x1.x) | ((u32)f2bf(x1.y) << 16);
        p.w = (u32)f2bf(x1.z) | ((u32)f2bf(x1.w) << 16);
        *(uint4*)&Wl[row][c8] = p;
    }
    #pragma unroll
    for (int i = 0; i < 4; ++i) {
        int c = i * 256 + tid;
        int row = c >> 4;
        int c8 = (c & 15) * 8;
        int n = nb + row;
        uint4 v = {0u, 0u, 0u, 0u};
        if (n < N) v = *(const uint4*)(meanA + (size_t)n * DIM + c8);
        *(uint4*)&Al[row][c8] = v;
    }
    __syncthreads();

    const int wave = tid >> 6;
    const int lane = tid & 63;
    const int m = lane & 15;
    const int quad = lane >> 4;

    v4f acc[8];
    #pragma unroll
    for (int t = 0; t < 8; ++t) acc[t] = (v4f){0.f, 0.f, 0.f, 0.f};

    const int arow = wave * 16 + m;
    #pragma unroll
    for (int k0 = 0; k0 < 128; k0 += 32) {
        v8s a = *(const v8s*)&Al[arow][k0 + quad * 8];
        #pragma unroll
        for (int t = 0; t < 8; ++t) {
            v8s b = *(const v8s*)&Wl[t * 16 + m][k0 + quad * 8];
            acc[t] = __builtin_amdgcn_mfma_f32_16x16x32_bf16(a, b, acc[t], 0, 0, 0);
        }
    }

    float bv[8];
    #pragma unroll
    for (int t = 0; t < 8; ++t) bv[t] = bias[t * 16 + m];

    #pragma unroll
    for (int r = 0; r < 4; ++r) {
        int n = nb + wave * 16 + quad * 4 + r;
        if (n >= N) continue;
        bool has = rowptr[n + 1] > rowptr[n];
        #pragma unroll
        for (int t = 0; t < 8; ++t) {
            float val = has ? (acc[t][r] + bv[t]) : 0.f;
            out[(size_t)n * DIM + t * 16 + m] = f2bf(val);
        }
    }
}

// ---------------- update (MFMA): relu([A1[n], B[n]] @ W^T + b) --------------
__global__ __launch_bounds__(256) void update_mfma(
    const void* __restrict__ A1, int a1_is_f32, const u16* __restrict__ B,
    const float* __restrict__ W, const float* __restrict__ bias,
    u16* __restrict__ outC, float* __restrict__ outF, int N)
{
    __shared__ u16 Wl[128][136];
    __shared__ u16 Al[64][136];
    const int tid = threadIdx.x;
    const int nb = blockIdx.x * 64;
    const int wave = tid >> 6;
    const int lane = tid & 63;
    const int m = lane & 15;
    const int quad = lane >> 4;

    v4f acc[8];
    #pragma unroll
    for (int t = 0; t < 8; ++t) acc[t] = (v4f){0.f, 0.f, 0.f, 0.f};

    for (int half = 0; half < 2; ++half) {
        if (half) __syncthreads();
        #pragma unroll
        for (int i = 0; i < 8; ++i) {
            int c = i * 256 + tid;
            int row = c >> 4;
            int c8 = (c & 15) * 8;
            const float4* wp = (const float4*)(W + row * 256 + half * 128 + c8);
            float4 x0 = wp[0], x1 = wp[1];
            uint4 p;
            p.x = (u32)f2bf(x0.x) | ((u32)f2bf(x0.y) << 16);
            p.y = (u32)f2bf(x0.z) | ((u32)f2bf(x0.w) << 16);
            p.z = (u32)f2bf(x1.x) | ((u32)f2bf(x1.y) << 16);
            p.w = (u32)f2bf(x1.z) | ((u32)f2bf(x1.w) << 16);
            *(uint4*)&Wl[row][c8] = p;
        }
        #pragma unroll
        for (int i = 0; i < 4; ++i) {
            int c = i * 256 + tid;
            int row = c >> 4;
            int c8 = (c & 15) * 8;
            int n = nb + row;
            uint4 v = {0u, 0u, 0u, 0u};
            if (n < N) {
                if (half == 0) {
                    if (a1_is_f32) {
                        const float4* ap = (const float4*)((const float*)A1 + (size_t)n * DIM + c8);
                        float4 x0 = ap[0], x1 = ap[1];
                        v.x = (u32)f2bf(x0.x) | ((u32)f2bf(x0.y) << 16);
                        v.y = (u32)f2bf(x0.z) | ((u32)f2bf(x0.w) << 16);
                        v.z = (u32)f2bf(x1.x) | ((u32)f2bf(x1.y) << 16);
                        v.w = (u32)f2bf(x1.z) | ((u32)f2bf(x1.w) << 16);
                    } else {
                        v = *(const uint4*)((const u16*)A1 + (size_t)n * DIM + c8);
                    }
                } else {
                    v = *(const uint4*)(B + (size_t)n * DIM + c8);
                }
            }
            *(uint4*)&Al[row][c8] = v;
        }
        __syncthreads();

        const int arow = wave * 16 + m;
        #pragma unroll
        for (int k0 = 0; k0 < 128; k0 += 32) {
            v8s a = *(const v8s*)&Al[arow][k0 + quad * 8];
            #pragma unroll
            for (int t = 0; t < 8; ++t) {
                v8s b = *(const v8s*)&Wl[t * 16 + m][k0 + quad * 8];
                acc[t] = __builtin_amdgcn_mfma_f32_16x16x32_bf16(a, b, acc[t], 0, 0, 0);
            }
        }
    }

    float bv[8];
    #pragma unroll
    for (int t = 0; t < 8; ++t) bv[t] = bias[t * 16 + m];

    #pragma unroll
    for (int r = 0; r < 4; ++r) {
        int n = nb + wave * 16 + quad * 4 + r;
        if (n >= N) continue;
        #pragma unroll
        for (int t = 0; t < 8; ++t) {
            float val = acc[t][r] + bv[t];
            val = val > 0.f ? val : 0.f;
            if (outC) outC[(size_t)n * DIM + t * 16 + m] = f2bf(val);
            if (outF) outF[(size_t)n * DIM + t * 16 + m] = val;
        }
    }
}

extern "C" void kernel_launch(void* const* d_in, const int* in_sizes, int n_in,
                              void* d_out, int out_size, void* d_ws, size_t ws_size,
                              hipStream_t stream)
{
    const float* tile_h   = (const float*)d_in[0];
    const float* piece_h  = (const float*)d_in[1];
    const int* tile_src   = (const int*)d_in[2];
    const int* piece_dst  = (const int*)d_in[3];
    const int* piece_src  = (const int*)d_in[4];
    const int* tile_dst   = (const int*)d_in[5];
    const int* t_src      = (const int*)d_in[6];
    const int* t_dst      = (const int*)d_in[7];
    const float* W_t2p = (const float*)d_in[8];
    const float* b_t2p = (const float*)d_in[9];
    const float* W_pu  = (const float*)d_in[10];
    const float* b_pu  = (const float*)d_in[11];
    const float* W_p2t = (const float*)d_in[12];
    const float* b_p2t = (const float*)d_in[13];
    const float* W_tup = (const float*)d_in[14];
    const float* b_tup = (const float*)d_in[15];
    const float* W_t2t = (const float*)d_in[16];
    const float* b_t2t = (const float*)d_in[17];
    const float* W_tut = (const float*)d_in[18];
    const float* b_tut = (const float*)d_in[19];

    const int NT  = in_sizes[0] / DIM;   // 50000
    const int NP  = in_sizes[1] / DIM;   // 25000
    const int EPT = in_sizes[2];         // 400000
    const int ETT = in_sizes[6];         // 600000
    const int EMX = (EPT > ETT) ? EPT : ETT;

    // ---- workspace layout (~42 MB) ----
    char* ws = (char*)d_ws;
    size_t off = 0;
    int* deg = (int*)(ws + off);      off += (size_t)NT * sizeof(int);
    int* cur = (int*)(ws + off);      off += (size_t)NT * sizeof(int);
    off = (off + 255) & ~(size_t)255;
    int* rowptr = (int*)(ws + off);   off += (size_t)(NT + 1) * sizeof(int);
    off = (off + 255) & ~(size_t)255;
    int* partial = (int*)(ws + off);  off += (size_t)NT * sizeof(int);
    int* blocksum = (int*)(ws + off); off += 64 * sizeof(int);
    off = (off + 255) & ~(size_t)255;
    int* elist = (int*)(ws + off);    off += (size_t)EMX * sizeof(int);
    off = (off + 255) & ~(size_t)255;
    u16* A = (u16*)(ws + off);        off += (size_t)NT * DIM * sizeof(u16);
    off = (off + 255) & ~(size_t)255;
    u16* B = (u16*)(ws + off);        off += (size_t)NT * DIM * sizeof(u16);
    off = (off + 255) & ~(size_t)255;
    u16* C = (u16*)(ws + off);        off += (size_t)NT * DIM * sizeof(u16);

    float* out_tile  = (float*)d_out;
    float* out_piece = out_tile + (size_t)NT * DIM;

    dim3 blk(256);
    dim3 g_zt((unsigned)((NT + 255) / 256));
    dim3 g_zp((unsigned)((NP + 255) / 256));
    dim3 g_e1((unsigned)((EPT + 255) / 256));
    dim3 g_e3((unsigned)((ETT + 255) / 256));
    dim3 g_sp((unsigned)((NP + 2047) / 2048));
    dim3 g_st((unsigned)((NT + 2047) / 2048));
    dim3 g_gp((unsigned)((NP + 7) / 8));
    dim3 g_gt((unsigned)((NT + 7) / 8));
    dim3 g_np((unsigned)((NP + 63) / 64));
    dim3 g_nt((unsigned)((NT + 63) / 64));

    // ---- Stage 1: tile -> piece ----
    hipLaunchKernelGGL(zeroi_kernel, g_zp, blk, 0, stream, deg, NP);
    hipLaunchKernelGGL(hist_kernel, g_e1, blk, 0, stream, piece_dst, EPT, deg);
    hipLaunchKernelGGL(scan_part, g_sp, blk, 0, stream, deg, partial, blocksum, NP);
    hipLaunchKernelGGL(scan_fix, g_sp, blk, 0, stream, partial, blocksum, rowptr, cur, NP, EPT);
    hipLaunchKernelGGL(fill_kernel, g_e1, blk, 0, stream,
                       tile_src, piece_dst, EPT, rowptr, cur, elist);
    hipLaunchKernelGGL(gather_mean_kernel, g_gp, blk, 0, stream,
                       (const void*)tile_h, 1, elist, rowptr, NP, A);
    hipLaunchKernelGGL(transform_mfma, g_np, blk, 0, stream,
                       A, rowptr, W_t2p, b_t2p, B, NP);
    hipLaunchKernelGGL(update_mfma, g_np, blk, 0, stream,
                       (const void*)piece_h, 1, B, W_pu, b_pu, C, out_piece, NP);

    // ---- Stage 2: piece -> tile ----
    hipLaunchKernelGGL(zeroi_kernel, g_zt, blk, 0, stream, deg, NT);
    hipLaunchKernelGGL(hist_kernel, g_e1, blk, 0, stream, tile_dst, EPT, deg);
    hipLaunchKernelGGL(scan_part, g_st, blk, 0, stream, deg, partial, blocksum, NT);
    hipLaunchKernelGGL(scan_fix, g_st, blk, 0, stream, partial, blocksum, rowptr, cur, NT, EPT);
    hipLaunchKernelGGL(fill_kernel, g_e1, blk, 0, stream,
                       piece_src, tile_dst, EPT, rowptr, cur, elist);
    hipLaunchKernelGGL(gather_mean_kernel, g_gt, blk, 0, stream,
                       (const void*)C, 0, elist, rowptr, NT, A);
    hipLaunchKernelGGL(transform_mfma, g_nt, blk, 0, stream,
                       A, rowptr, W_p2t, b_p2t, B, NT);
    hipLaunchKernelGGL(update_mfma, g_nt, blk, 0, stream,
                       (const void*)tile_h, 1, B, W_tup, b_tup, C, (float*)nullptr, NT);

    // ---- Stage 3: tile -> tile ----
    hipLaunchKernelGGL(zeroi_kernel, g_zt, blk, 0, stream, deg, NT);
    hipLaunchKernelGGL(hist_kernel, g_e3, blk, 0, stream, t_dst, ETT, deg);
    hipLaunchKernelGGL(scan_part, g_st, blk, 0, stream, deg, partial, blocksum, NT);
    hipLaunchKernelGGL(scan_fix, g_st, blk, 0, stream, partial, blocksum, rowptr, cur, NT, ETT);
    hipLaunchKernelGGL(fill_kernel, g_e3, blk, 0, stream,
                       t_src, t_dst, ETT, rowptr, cur, elist);
    hipLaunchKernelGGL(gather_mean_kernel, g_gt, blk, 0, stream,
                       (const void*)C, 0, elist, rowptr, NT, A);
    hipLaunchKernelGGL(transform_mfma, g_nt, blk, 0, stream,
                       A, rowptr, W_t2t, b_t2t, B, NT);
    hipLaunchKernelGGL(update_mfma, g_nt, blk, 0, stream,
                       (const void*)C, 0, B, W_tut, b_tut, (u16*)nullptr, out_tile, NT);
}

// Round 9
// 448.328 us; speedup vs baseline: 7.1317x; 1.0972x over previous
//
#include <hip/hip_runtime.h>
#include <hip/hip_bf16.h>

#define DIM 128

typedef unsigned short u16;
typedef unsigned int u32;
typedef __attribute__((ext_vector_type(8))) short v8s;
typedef __attribute__((ext_vector_type(4))) float v4f;

__device__ __forceinline__ float bf2f(u16 u) {
    union { unsigned int i; float f; } v;
    v.i = ((unsigned int)u) << 16;
    return v.f;
}

__device__ __forceinline__ u16 f2bf(float f) {
    union { float f; unsigned int i; } v;
    v.f = f;
    unsigned int x = v.i;
    return (u16)((x + 0x7fffu + ((x >> 16) & 1u)) >> 16);
}

__device__ __forceinline__ uint4 pack8(float4 x0, float4 x1) {
    uint4 o;
    o.x = (u32)f2bf(x0.x) | ((u32)f2bf(x0.y) << 16);
    o.y = (u32)f2bf(x0.z) | ((u32)f2bf(x0.w) << 16);
    o.z = (u32)f2bf(x1.x) | ((u32)f2bf(x1.y) << 16);
    o.w = (u32)f2bf(x1.z) | ((u32)f2bf(x1.w) << 16);
    return o;
}

// ---------------- f32 -> bf16 conversion kernels ----------------------------
__global__ __launch_bounds__(256) void cvt_kernel(const float* __restrict__ src,
                                                  u16* __restrict__ dst, int n8)
{
    int g = blockIdx.x * 256 + threadIdx.x;
    if (g >= n8) return;
    const float4* fp = (const float4*)(src + (size_t)g * 8);
    *(uint4*)(dst + (size_t)g * 8) = pack8(fp[0], fp[1]);
}

// all 6 weight matrices in one launch (total 147456 elems = 18432 chunks)
struct W6 { const float* s[6]; };
__global__ __launch_bounds__(256) void cvtw_kernel(W6 a, u16* __restrict__ dst)
{
    int g = blockIdx.x * 256 + threadIdx.x;           // grid = 72 blocks exactly
    u32 flat = (u32)g * 8;
    int seg; u32 base;
    if      (flat < 16384u)  { seg = 0; base = 0u; }
    else if (flat < 49152u)  { seg = 1; base = 16384u; }
    else if (flat < 65536u)  { seg = 2; base = 49152u; }
    else if (flat < 98304u)  { seg = 3; base = 65536u; }
    else if (flat < 114688u) { seg = 4; base = 98304u; }
    else                     { seg = 5; base = 114688u; }
    const float4* fp = (const float4*)(a.s[seg] + (flat - base));
    *(uint4*)(dst + flat) = pack8(fp[0], fp[1]);
}

// ---------------- zero-fill ints --------------------------------------------
__global__ __launch_bounds__(256) void zeroi_kernel(int* __restrict__ p, int n)
{
    int i = blockIdx.x * 256 + threadIdx.x;
    if (i < n) p[i] = 0;
}

// ---------------- CSR build: histogram --------------------------------------
__global__ __launch_bounds__(256) void hist_kernel(const int* __restrict__ dst, int E,
                                                   int* __restrict__ deg)
{
    int e = blockIdx.x * 256 + threadIdx.x;
    if (e < E) atomicAdd(&deg[dst[e]], 1);
}

// ---------------- two-level exclusive scan ----------------------------------
__global__ __launch_bounds__(256) void scan_part(const int* __restrict__ deg,
                                                 int* __restrict__ partial,
                                                 int* __restrict__ blocksum, int N)
{
    __shared__ int ls[256];
    const int base = blockIdx.x * 2048;
    const int t = threadIdx.x;
    int v[8];
    int s = 0;
    #pragma unroll
    for (int i = 0; i < 8; ++i) {
        int idx = base + t * 8 + i;
        v[i] = (idx < N) ? deg[idx] : 0;
        s += v[i];
    }
    ls[t] = s;
    __syncthreads();
    #pragma unroll
    for (int o = 1; o < 256; o <<= 1) {
        int x = (t >= o) ? ls[t - o] : 0;
        __syncthreads();
        ls[t] += x;
        __syncthreads();
    }
    int run = (t == 0) ? 0 : ls[t - 1];
    #pragma unroll
    for (int i = 0; i < 8; ++i) {
        int idx = base + t * 8 + i;
        if (idx < N) partial[idx] = run;
        run += v[i];
    }
    if (t == 255) blocksum[blockIdx.x] = ls[255];
}

__global__ __launch_bounds__(256) void scan_fix(const int* __restrict__ partial,
                                                const int* __restrict__ blocksum,
                                                int* __restrict__ rowptr,
                                                int* __restrict__ cur, int N, int E)
{
    __shared__ int off_s;
    const int base = blockIdx.x * 2048;
    const int t = threadIdx.x;
    if (t == 0) {
        int o = 0;
        for (int b = 0; b < (int)blockIdx.x; ++b) o += blocksum[b];
        off_s = o;
    }
    __syncthreads();
    const int off = off_s;
    #pragma unroll
    for (int i = 0; i < 8; ++i) {
        int idx = base + t * 8 + i;
        if (idx < N) { rowptr[idx] = partial[idx] + off; cur[idx] = 0; }
    }
    if (blockIdx.x == gridDim.x - 1 && t == 255) rowptr[N] = E;
}

// ---------------- CSR fill --------------------------------------------------
__global__ __launch_bounds__(256) void fill_kernel(const int* __restrict__ src,
                                                   const int* __restrict__ dst, int E,
                                                   const int* __restrict__ rowptr,
                                                   int* __restrict__ cur,
                                                   int* __restrict__ elist)
{
    int e = blockIdx.x * 256 + threadIdx.x;
    if (e >= E) return;
    int d = dst[e];
    int pos = atomicAdd(&cur[d], 1);
    elist[rowptr[d] + pos] = src[e];
}

// ---------------- gather-side mean, 4-wide ILP ------------------------------
// 32 lanes/node, 4 feats/lane; 4 independent row loads in flight.
__global__ __launch_bounds__(256) void gather_mean_kernel(
    const u16* __restrict__ feat,
    const int* __restrict__ elist, const int* __restrict__ rowptr,
    int N, u16* __restrict__ meanA)
{
    int node = blockIdx.x * 8 + (threadIdx.x >> 5);
    int lane = threadIdx.x & 31;
    if (node >= N) return;
    int r0 = rowptr[node], r1 = rowptr[node + 1];
    float a0 = 0.f, a1 = 0.f, a2 = 0.f, a3 = 0.f;
    float b0 = 0.f, b1 = 0.f, b2 = 0.f, b3 = 0.f;
    int j = r0;
    for (; j + 4 <= r1; j += 4) {
        int s0 = elist[j], s1 = elist[j + 1], s2 = elist[j + 2], s3 = elist[j + 3];
        uint2 v0 = ((const uint2*)(feat + (size_t)s0 * DIM))[lane];
        uint2 v1 = ((const uint2*)(feat + (size_t)s1 * DIM))[lane];
        uint2 v2 = ((const uint2*)(feat + (size_t)s2 * DIM))[lane];
        uint2 v3 = ((const uint2*)(feat + (size_t)s3 * DIM))[lane];
        a0 += bf2f((u16)(v0.x & 0xffffu)); a1 += bf2f((u16)(v0.x >> 16));
        a2 += bf2f((u16)(v0.y & 0xffffu)); a3 += bf2f((u16)(v0.y >> 16));
        b0 += bf2f((u16)(v1.x & 0xffffu)); b1 += bf2f((u16)(v1.x >> 16));
        b2 += bf2f((u16)(v1.y & 0xffffu)); b3 += bf2f((u16)(v1.y >> 16));
        a0 += bf2f((u16)(v2.x & 0xffffu)); a1 += bf2f((u16)(v2.x >> 16));
        a2 += bf2f((u16)(v2.y & 0xffffu)); a3 += bf2f((u16)(v2.y >> 16));
        b0 += bf2f((u16)(v3.x & 0xffffu)); b1 += bf2f((u16)(v3.x >> 16));
        b2 += bf2f((u16)(v3.y & 0xffffu)); b3 += bf2f((u16)(v3.y >> 16));
    }
    for (; j < r1; ++j) {
        int s = elist[j];
        uint2 v = ((const uint2*)(feat + (size_t)s * DIM))[lane];
        a0 += bf2f((u16)(v.x & 0xffffu)); a1 += bf2f((u16)(v.x >> 16));
        a2 += bf2f((u16)(v.y & 0xffffu)); a3 += bf2f((u16)(v.y >> 16));
    }
    a0 += b0; a1 += b1; a2 += b2; a3 += b3;
    float sc = (r1 > r0) ? (1.f / (float)(r1 - r0)) : 0.f;
    uint2 o;
    o.x = (u32)f2bf(a0 * sc) | ((u32)f2bf(a1 * sc) << 16);
    o.y = (u32)f2bf(a2 * sc) | ((u32)f2bf(a3 * sc) << 16);
    ((uint2*)(meanA + (size_t)node * DIM))[lane] = o;
}

// ---------------- transform (MFMA): B[n] = deg>0 ? W*meanA[n] + b : 0 -------
// W pre-converted bf16 [128][128].
__global__ __launch_bounds__(256) void transform_mfma(
    const u16* __restrict__ meanA, const int* __restrict__ rowptr,
    const u16* __restrict__ W, const float* __restrict__ bias,
    u16* __restrict__ out, int N)
{
    __shared__ u16 Wl[128][136];
    __shared__ u16 Al[64][136];
    const int tid = threadIdx.x;
    const int nb = blockIdx.x * 64;

    #pragma unroll
    for (int i = 0; i < 8; ++i) {
        int c = i * 256 + tid;
        int row = c >> 4;
        int c8 = (c & 15) * 8;
        *(uint4*)&Wl[row][c8] = *(const uint4*)(W + row * 128 + c8);
    }
    #pragma unroll
    for (int i = 0; i < 4; ++i) {
        int c = i * 256 + tid;
        int row = c >> 4;
        int c8 = (c & 15) * 8;
        int n = nb + row;
        uint4 v = {0u, 0u, 0u, 0u};
        if (n < N) v = *(const uint4*)(meanA + (size_t)n * DIM + c8);
        *(uint4*)&Al[row][c8] = v;
    }
    __syncthreads();

    const int wave = tid >> 6;
    const int lane = tid & 63;
    const int m = lane & 15;
    const int quad = lane >> 4;

    v4f acc[8];
    #pragma unroll
    for (int t = 0; t < 8; ++t) acc[t] = (v4f){0.f, 0.f, 0.f, 0.f};

    const int arow = wave * 16 + m;
    #pragma unroll
    for (int k0 = 0; k0 < 128; k0 += 32) {
        v8s a = *(const v8s*)&Al[arow][k0 + quad * 8];
        #pragma unroll
        for (int t = 0; t < 8; ++t) {
            v8s b = *(const v8s*)&Wl[t * 16 + m][k0 + quad * 8];
            acc[t] = __builtin_amdgcn_mfma_f32_16x16x32_bf16(a, b, acc[t], 0, 0, 0);
        }
    }

    float bv[8];
    #pragma unroll
    for (int t = 0; t < 8; ++t) bv[t] = bias[t * 16 + m];

    #pragma unroll
    for (int r = 0; r < 4; ++r) {
        int n = nb + wave * 16 + quad * 4 + r;
        if (n >= N) continue;
        bool has = rowptr[n + 1] > rowptr[n];
        #pragma unroll
        for (int t = 0; t < 8; ++t) {
            float val = has ? (acc[t][r] + bv[t]) : 0.f;
            out[(size_t)n * DIM + t * 16 + m] = f2bf(val);
        }
    }
}

// ---------------- update (MFMA): relu([A1[n], B[n]] @ W^T + b) --------------
// W pre-converted bf16 [128][256]; A1 bf16.
__global__ __launch_bounds__(256) void update_mfma(
    const u16* __restrict__ A1, const u16* __restrict__ B,
    const u16* __restrict__ W, const float* __restrict__ bias,
    u16* __restrict__ outC, float* __restrict__ outF, int N)
{
    __shared__ u16 Wl[128][136];
    __shared__ u16 Al[64][136];
    const int tid = threadIdx.x;
    const int nb = blockIdx.x * 64;
    const int wave = tid >> 6;
    const int lane = tid & 63;
    const int m = lane & 15;
    const int quad = lane >> 4;

    v4f acc[8];
    #pragma unroll
    for (int t = 0; t < 8; ++t) acc[t] = (v4f){0.f, 0.f, 0.f, 0.f};

    for (int half = 0; half < 2; ++half) {
        if (half) __syncthreads();
        const u16* Asrc = half ? B : A1;
        #pragma unroll
        for (int i = 0; i < 8; ++i) {
            int c = i * 256 + tid;
            int row = c >> 4;
            int c8 = (c & 15) * 8;
            *(uint4*)&Wl[row][c8] = *(const uint4*)(W + row * 256 + half * 128 + c8);
        }
        #pragma unroll
        for (int i = 0; i < 4; ++i) {
            int c = i * 256 + tid;
            int row = c >> 4;
            int c8 = (c & 15) * 8;
            int n = nb + row;
            uint4 v = {0u, 0u, 0u, 0u};
            if (n < N) v = *(const uint4*)(Asrc + (size_t)n * DIM + c8);
            *(uint4*)&Al[row][c8] = v;
        }
        __syncthreads();

        const int arow = wave * 16 + m;
        #pragma unroll
        for (int k0 = 0; k0 < 128; k0 += 32) {
            v8s a = *(const v8s*)&Al[arow][k0 + quad * 8];
            #pragma unroll
            for (int t = 0; t < 8; ++t) {
                v8s b = *(const v8s*)&Wl[t * 16 + m][k0 + quad * 8];
                acc[t] = __builtin_amdgcn_mfma_f32_16x16x32_bf16(a, b, acc[t], 0, 0, 0);
            }
        }
    }

    float bv[8];
    #pragma unroll
    for (int t = 0; t < 8; ++t) bv[t] = bias[t * 16 + m];

    #pragma unroll
    for (int r = 0; r < 4; ++r) {
        int n = nb + wave * 16 + quad * 4 + r;
        if (n >= N) continue;
        #pragma unroll
        for (int t = 0; t < 8; ++t) {
            float val = acc[t][r] + bv[t];
            val = val > 0.f ? val : 0.f;
            if (outC) outC[(size_t)n * DIM + t * 16 + m] = f2bf(val);
            if (outF) outF[(size_t)n * DIM + t * 16 + m] = val;
        }
    }
}

extern "C" void kernel_launch(void* const* d_in, const int* in_sizes, int n_in,
                              void* d_out, int out_size, void* d_ws, size_t ws_size,
                              hipStream_t stream)
{
    const float* tile_h   = (const float*)d_in[0];
    const float* piece_h  = (const float*)d_in[1];
    const int* tile_src   = (const int*)d_in[2];
    const int* piece_dst  = (const int*)d_in[3];
    const int* piece_src  = (const int*)d_in[4];
    const int* tile_dst   = (const int*)d_in[5];
    const int* t_src      = (const int*)d_in[6];
    const int* t_dst      = (const int*)d_in[7];
    const float* b_t2p = (const float*)d_in[9];
    const float* b_pu  = (const float*)d_in[11];
    const float* b_p2t = (const float*)d_in[13];
    const float* b_tup = (const float*)d_in[15];
    const float* b_t2t = (const float*)d_in[17];
    const float* b_tut = (const float*)d_in[19];

    const int NT  = in_sizes[0] / DIM;   // 50000
    const int NP  = in_sizes[1] / DIM;   // 25000
    const int EPT = in_sizes[2];         // 400000
    const int ETT = in_sizes[6];         // 600000
    const int EMX = (EPT > ETT) ? EPT : ETT;

    // ---- workspace layout (~62 MB) ----
    char* ws = (char*)d_ws;
    size_t off = 0;
    int* deg = (int*)(ws + off);      off += (size_t)NT * sizeof(int);
    int* cur = (int*)(ws + off);      off += (size_t)NT * sizeof(int);
    off = (off + 255) & ~(size_t)255;
    int* rowptr = (int*)(ws + off);   off += (size_t)(NT + 1) * sizeof(int);
    off = (off + 255) & ~(size_t)255;
    int* partial = (int*)(ws + off);  off += (size_t)NT * sizeof(int);
    int* blocksum = (int*)(ws + off); off += 64 * sizeof(int);
    off = (off + 255) & ~(size_t)255;
    int* elist = (int*)(ws + off);    off += (size_t)EMX * sizeof(int);
    off = (off + 255) & ~(size_t)255;
    u16* A = (u16*)(ws + off);        off += (size_t)NT * DIM * sizeof(u16);
    off = (off + 255) & ~(size_t)255;
    u16* B = (u16*)(ws + off);        off += (size_t)NT * DIM * sizeof(u16);
    off = (off + 255) & ~(size_t)255;
    u16* C = (u16*)(ws + off);        off += (size_t)NT * DIM * sizeof(u16);
    off = (off + 255) & ~(size_t)255;
    u16* Th = (u16*)(ws + off);       off += (size_t)NT * DIM * sizeof(u16);  // tile_h bf16
    off = (off + 255) & ~(size_t)255;
    u16* Ph = (u16*)(ws + off);       off += (size_t)NP * DIM * sizeof(u16);  // piece_h bf16
    off = (off + 255) & ~(size_t)255;
    u16* Wc = (u16*)(ws + off);       off += 147456 * sizeof(u16);            // 6 weights bf16

    const u16* Wt2p = Wc + 0;
    const u16* Wpu  = Wc + 16384;
    const u16* Wp2t = Wc + 49152;
    const u16* Wtup = Wc + 65536;
    const u16* Wt2t = Wc + 98304;
    const u16* Wtut = Wc + 114688;

    float* out_tile  = (float*)d_out;
    float* out_piece = out_tile + (size_t)NT * DIM;

    dim3 blk(256);
    dim3 g_zt((unsigned)((NT + 255) / 256));
    dim3 g_zp((unsigned)((NP + 255) / 256));
    dim3 g_e1((unsigned)((EPT + 255) / 256));
    dim3 g_e3((unsigned)((ETT + 255) / 256));
    dim3 g_sp((unsigned)((NP + 2047) / 2048));
    dim3 g_st((unsigned)((NT + 2047) / 2048));
    dim3 g_gp((unsigned)((NP + 7) / 8));
    dim3 g_gt((unsigned)((NT + 7) / 8));
    dim3 g_np((unsigned)((NP + 63) / 64));
    dim3 g_nt((unsigned)((NT + 63) / 64));

    // ---- pre-convert to bf16 ----
    int nTh8 = NT * DIM / 8, nPh8 = NP * DIM / 8;
    hipLaunchKernelGGL(cvt_kernel, dim3((nTh8 + 255) / 256), blk, 0, stream,
                       tile_h, Th, nTh8);
    hipLaunchKernelGGL(cvt_kernel, dim3((nPh8 + 255) / 256), blk, 0, stream,
                       piece_h, Ph, nPh8);
    W6 w6;
    w6.s[0] = (const float*)d_in[8];  w6.s[1] = (const float*)d_in[10];
    w6.s[2] = (const float*)d_in[12]; w6.s[3] = (const float*)d_in[14];
    w6.s[4] = (const float*)d_in[16]; w6.s[5] = (const float*)d_in[18];
    hipLaunchKernelGGL(cvtw_kernel, dim3(72), blk, 0, stream, w6, Wc);

    // ---- Stage 1: tile -> piece ----
    hipLaunchKernelGGL(zeroi_kernel, g_zp, blk, 0, stream, deg, NP);
    hipLaunchKernelGGL(hist_kernel, g_e1, blk, 0, stream, piece_dst, EPT, deg);
    hipLaunchKernelGGL(scan_part, g_sp, blk, 0, stream, deg, partial, blocksum, NP);
    hipLaunchKernelGGL(scan_fix, g_sp, blk, 0, stream, partial, blocksum, rowptr, cur, NP, EPT);
    hipLaunchKernelGGL(fill_kernel, g_e1, blk, 0, stream,
                       tile_src, piece_dst, EPT, rowptr, cur, elist);
    hipLaunchKernelGGL(gather_mean_kernel, g_gp, blk, 0, stream,
                       Th, elist, rowptr, NP, A);
    hipLaunchKernelGGL(transform_mfma, g_np, blk, 0, stream,
                       A, rowptr, Wt2p, b_t2p, B, NP);
    hipLaunchKernelGGL(update_mfma, g_np, blk, 0, stream,
                       Ph, B, Wpu, b_pu, C, out_piece, NP);

    // ---- Stage 2: piece -> tile ----
    hipLaunchKernelGGL(zeroi_kernel, g_zt, blk, 0, stream, deg, NT);
    hipLaunchKernelGGL(hist_kernel, g_e1, blk, 0, stream, tile_dst, EPT, deg);
    hipLaunchKernelGGL(scan_part, g_st, blk, 0, stream, deg, partial, blocksum, NT);
    hipLaunchKernelGGL(scan_fix, g_st, blk, 0, stream, partial, blocksum, rowptr, cur, NT, EPT);
    hipLaunchKernelGGL(fill_kernel, g_e1, blk, 0, stream,
                       piece_src, tile_dst, EPT, rowptr, cur, elist);
    hipLaunchKernelGGL(gather_mean_kernel, g_gt, blk, 0, stream,
                       C, elist, rowptr, NT, A);
    hipLaunchKernelGGL(transform_mfma, g_nt, blk, 0, stream,
                       A, rowptr, Wp2t, b_p2t, B, NT);
    hipLaunchKernelGGL(update_mfma, g_nt, blk, 0, stream,
                       Th, B, Wtup, b_tup, C, (float*)nullptr, NT);

    // ---- Stage 3: tile -> tile ----
    hipLaunchKernelGGL(zeroi_kernel, g_zt, blk, 0, stream, deg, NT);
    hipLaunchKernelGGL(hist_kernel, g_e3, blk, 0, stream, t_dst, ETT, deg);
    hipLaunchKernelGGL(scan_part, g_st, blk, 0, stream, deg, partial, blocksum, NT);
    hipLaunchKernelGGL(scan_fix, g_st, blk, 0, stream, partial, blocksum, rowptr, cur, NT, ETT);
    hipLaunchKernelGGL(fill_kernel, g_e3, blk, 0, stream,
                       t_src, t_dst, ETT, rowptr, cur, elist);
    hipLaunchKernelGGL(gather_mean_kernel, g_gt, blk, 0, stream,
                       C, elist, rowptr, NT, A);
    hipLaunchKernelGGL(transform_mfma, g_nt, blk, 0, stream,
                       A, rowptr, Wt2t, b_t2t, B, NT);
    hipLaunchKernelGGL(update_mfma, g_nt, blk, 0, stream,
                       C, B, Wtut, b_tut, (u16*)nullptr, out_tile, NT);
}

// Round 10
// 384.849 us; speedup vs baseline: 8.3080x; 1.1649x over previous
//
#include <hip/hip_runtime.h>
#include <hip/hip_bf16.h>

#define DIM 128

typedef unsigned short u16;
typedef unsigned int u32;
typedef __attribute__((ext_vector_type(8))) short v8s;
typedef __attribute__((ext_vector_type(4))) float v4f;

__device__ __forceinline__ float bf2f(u16 u) {
    union { unsigned int i; float f; } v;
    v.i = ((unsigned int)u) << 16;
    return v.f;
}

__device__ __forceinline__ u16 f2bf(float f) {
    union { float f; unsigned int i; } v;
    v.f = f;
    unsigned int x = v.i;
    return (u16)((x + 0x7fffu + ((x >> 16) & 1u)) >> 16);
}

__device__ __forceinline__ uint4 pack8(float4 x0, float4 x1) {
    uint4 o;
    o.x = (u32)f2bf(x0.x) | ((u32)f2bf(x0.y) << 16);
    o.y = (u32)f2bf(x0.z) | ((u32)f2bf(x0.w) << 16);
    o.z = (u32)f2bf(x1.x) | ((u32)f2bf(x1.y) << 16);
    o.w = (u32)f2bf(x1.z) | ((u32)f2bf(x1.w) << 16);
    return o;
}

// ---------------- one-shot f32 -> bf16 conversion (8 segments) --------------
struct CvtArgs { const float* s[8]; u32 pfx[9]; };
__global__ __launch_bounds__(256) void cvt_all(CvtArgs a, u16* __restrict__ dst, int n8)
{
    int g = blockIdx.x * 256 + threadIdx.x;
    if (g >= n8) return;
    u32 flat = (u32)g * 8;
    int seg = 0;
    #pragma unroll
    for (int i = 1; i < 8; ++i) if (flat >= a.pfx[i]) seg = i;
    const float4* fp = (const float4*)(a.s[seg] + (flat - a.pfx[seg]));
    *(uint4*)(dst + flat) = pack8(fp[0], fp[1]);
}

// ---------------- zero-fill ints --------------------------------------------
__global__ __launch_bounds__(256) void zeroi_kernel(int* __restrict__ p, int n)
{
    int i = blockIdx.x * 256 + threadIdx.x;
    if (i < n) p[i] = 0;
}

// ---------------- combined histogram (3 stages, deg arena) ------------------
__global__ __launch_bounds__(256) void hist3(
    const int* __restrict__ piece_dst, const int* __restrict__ tile_dst,
    const int* __restrict__ t_dst, int EPT, int ETT,
    int* __restrict__ deg, int NP, int NT)
{
    int e = blockIdx.x * 256 + threadIdx.x;
    if (e < EPT)               atomicAdd(&deg[piece_dst[e]], 1);
    else if (e < 2 * EPT)      atomicAdd(&deg[NP + tile_dst[e - EPT]], 1);
    else if (e < 2 * EPT + ETT) atomicAdd(&deg[NP + NT + t_dst[e - 2 * EPT]], 1);
}

// ---------------- combined two-level scan -----------------------------------
// segments: [NP | NT | NT] in deg/partial/cur arenas; rowptr arena has +1 gaps.
__global__ __launch_bounds__(256) void scan_part3(const int* __restrict__ deg,
                                                  int* __restrict__ partial,
                                                  int* __restrict__ bsum,
                                                  int NP, int NT)
{
    const int B1 = (NP + 2047) >> 11, B2 = (NT + 2047) >> 11;
    int b = blockIdx.x, lb, Nseg, base, bsb;
    if (b < B1)           { lb = b;            Nseg = NP; base = 0;       bsb = 0;  }
    else if (b < B1 + B2) { lb = b - B1;       Nseg = NT; base = NP;      bsb = 16; }
    else                  { lb = b - B1 - B2;  Nseg = NT; base = NP + NT; bsb = 64; }

    __shared__ int ls[256];
    const int lbase = lb * 2048;
    const int t = threadIdx.x;
    int v[8];
    int s = 0;
    #pragma unroll
    for (int i = 0; i < 8; ++i) {
        int idx = lbase + t * 8 + i;
        v[i] = (idx < Nseg) ? deg[base + idx] : 0;
        s += v[i];
    }
    ls[t] = s;
    __syncthreads();
    #pragma unroll
    for (int o = 1; o < 256; o <<= 1) {
        int x = (t >= o) ? ls[t - o] : 0;
        __syncthreads();
        ls[t] += x;
        __syncthreads();
    }
    int run = (t == 0) ? 0 : ls[t - 1];
    #pragma unroll
    for (int i = 0; i < 8; ++i) {
        int idx = lbase + t * 8 + i;
        if (idx < Nseg) partial[base + idx] = run;
        run += v[i];
    }
    if (t == 255) bsum[bsb + lb] = ls[255];
}

__global__ __launch_bounds__(256) void scan_fix3(const int* __restrict__ partial,
                                                 const int* __restrict__ bsum,
                                                 int* __restrict__ rowptr,
                                                 int* __restrict__ cur,
                                                 int NP, int NT, int EPT, int ETT)
{
    const int B1 = (NP + 2047) >> 11, B2 = (NT + 2047) >> 11;
    int b = blockIdx.x, lb, Nseg, base, bsb, rb, Eseg;
    if (b < B1)           { lb = b;           Nseg = NP; base = 0;       bsb = 0;  rb = 0;                  Eseg = EPT; }
    else if (b < B1 + B2) { lb = b - B1;      Nseg = NT; base = NP;      bsb = 16; rb = NP + 1;             Eseg = EPT; }
    else                  { lb = b - B1 - B2; Nseg = NT; base = NP + NT; bsb = 64; rb = NP + 1 + NT + 1;    Eseg = ETT; }

    __shared__ int off_s;
    const int t = threadIdx.x;
    if (t == 0) {
        int o = 0;
        for (int i = 0; i < lb; ++i) o += bsum[bsb + i];
        off_s = o;
    }
    __syncthreads();
    const int off = off_s;
    const int lbase = lb * 2048;
    #pragma unroll
    for (int i = 0; i < 8; ++i) {
        int idx = lbase + t * 8 + i;
        if (idx < Nseg) {
            rowptr[rb + idx] = partial[base + idx] + off;
            cur[base + idx] = 0;
        }
    }
    int lastlb = ((Nseg + 2047) >> 11) - 1;
    if (lb == lastlb && t == 255) rowptr[rb + Nseg] = Eseg;
}

// ---------------- combined CSR fill -----------------------------------------
__global__ __launch_bounds__(256) void fill3(
    const int* __restrict__ tile_src, const int* __restrict__ piece_dst,
    const int* __restrict__ piece_src, const int* __restrict__ tile_dst,
    const int* __restrict__ t_src, const int* __restrict__ t_dst,
    int EPT, int ETT,
    const int* __restrict__ rowptr, int* __restrict__ cur,
    int* __restrict__ el1, int* __restrict__ el2, int* __restrict__ el3,
    int NP, int NT)
{
    int e = blockIdx.x * 256 + threadIdx.x;
    int d, s;
    const int* rp; int* curp; int* el;
    if (e < EPT) {
        d = piece_dst[e]; s = tile_src[e];
        rp = rowptr; curp = cur; el = el1;
    } else if (e < 2 * EPT) {
        int le = e - EPT;
        d = tile_dst[le]; s = piece_src[le];
        rp = rowptr + NP + 1; curp = cur + NP; el = el2;
    } else if (e < 2 * EPT + ETT) {
        int le = e - 2 * EPT;
        d = t_dst[le]; s = t_src[le];
        rp = rowptr + NP + 1 + NT + 1; curp = cur + NP + NT; el = el3;
    } else return;
    int pos = atomicAdd(&curp[d], 1);
    el[rp[d] + pos] = s;
}

// ---------------- gather-side mean, 4-wide ILP ------------------------------
__global__ __launch_bounds__(256) void gather_mean_kernel(
    const u16* __restrict__ feat,
    const int* __restrict__ elist, const int* __restrict__ rowptr,
    int N, u16* __restrict__ meanA)
{
    int node = blockIdx.x * 8 + (threadIdx.x >> 5);
    int lane = threadIdx.x & 31;
    if (node >= N) return;
    int r0 = rowptr[node], r1 = rowptr[node + 1];
    float a0 = 0.f, a1 = 0.f, a2 = 0.f, a3 = 0.f;
    float b0 = 0.f, b1 = 0.f, b2 = 0.f, b3 = 0.f;
    int j = r0;
    for (; j + 4 <= r1; j += 4) {
        int s0 = elist[j], s1 = elist[j + 1], s2 = elist[j + 2], s3 = elist[j + 3];
        uint2 v0 = ((const uint2*)(feat + (size_t)s0 * DIM))[lane];
        uint2 v1 = ((const uint2*)(feat + (size_t)s1 * DIM))[lane];
        uint2 v2 = ((const uint2*)(feat + (size_t)s2 * DIM))[lane];
        uint2 v3 = ((const uint2*)(feat + (size_t)s3 * DIM))[lane];
        a0 += bf2f((u16)(v0.x & 0xffffu)); a1 += bf2f((u16)(v0.x >> 16));
        a2 += bf2f((u16)(v0.y & 0xffffu)); a3 += bf2f((u16)(v0.y >> 16));
        b0 += bf2f((u16)(v1.x & 0xffffu)); b1 += bf2f((u16)(v1.x >> 16));
        b2 += bf2f((u16)(v1.y & 0xffffu)); b3 += bf2f((u16)(v1.y >> 16));
        a0 += bf2f((u16)(v2.x & 0xffffu)); a1 += bf2f((u16)(v2.x >> 16));
        a2 += bf2f((u16)(v2.y & 0xffffu)); a3 += bf2f((u16)(v2.y >> 16));
        b0 += bf2f((u16)(v3.x & 0xffffu)); b1 += bf2f((u16)(v3.x >> 16));
        b2 += bf2f((u16)(v3.y & 0xffffu)); b3 += bf2f((u16)(v3.y >> 16));
    }
    for (; j < r1; ++j) {
        int s = elist[j];
        uint2 v = ((const uint2*)(feat + (size_t)s * DIM))[lane];
        a0 += bf2f((u16)(v.x & 0xffffu)); a1 += bf2f((u16)(v.x >> 16));
        a2 += bf2f((u16)(v.y & 0xffffu)); a3 += bf2f((u16)(v.y >> 16));
    }
    a0 += b0; a1 += b1; a2 += b2; a3 += b3;
    float sc = (r1 > r0) ? (1.f / (float)(r1 - r0)) : 0.f;
    uint2 o;
    o.x = (u32)f2bf(a0 * sc) | ((u32)f2bf(a1 * sc) << 16);
    o.y = (u32)f2bf(a2 * sc) | ((u32)f2bf(a3 * sc) << 16);
    ((uint2*)(meanA + (size_t)node * DIM))[lane] = o;
}

// ---------------- fused transform+update per stage --------------------------
// B = (deg>0) ? meanA @ Wt^T + bt : 0   (kept in LDS)
// out = relu([A1, B] @ Wu^T + bu)
__global__ __launch_bounds__(256) void stage_fused(
    const u16* __restrict__ meanA, const int* __restrict__ rowptr,
    const u16* __restrict__ Wt, const float* __restrict__ bt,
    const u16* __restrict__ A1, const u16* __restrict__ Wu,
    const float* __restrict__ bu,
    u16* __restrict__ outC, float* __restrict__ outF, int N)
{
    __shared__ u16 Wl[128][136];
    __shared__ u16 Al[64][136];
    __shared__ u16 Bl[64][136];
    const int tid = threadIdx.x;
    const int nb = blockIdx.x * 64;
    const int wave = tid >> 6;
    const int lane = tid & 63;
    const int m = lane & 15;
    const int quad = lane >> 4;
    const int arow = wave * 16 + m;

    // ---- stage Wt + meanA ----
    #pragma unroll
    for (int i = 0; i < 8; ++i) {
        int c = i * 256 + tid;
        int row = c >> 4;
        int c8 = (c & 15) * 8;
        *(uint4*)&Wl[row][c8] = *(const uint4*)(Wt + row * 128 + c8);
    }
    #pragma unroll
    for (int i = 0; i < 4; ++i) {
        int c = i * 256 + tid;
        int row = c >> 4;
        int c8 = (c & 15) * 8;
        int n = nb + row;
        uint4 v = {0u, 0u, 0u, 0u};
        if (n < N) v = *(const uint4*)(meanA + (size_t)n * DIM + c8);
        *(uint4*)&Al[row][c8] = v;
    }
    __syncthreads();

    // ---- transform MFMA ----
    v4f acct[8];
    #pragma unroll
    for (int t = 0; t < 8; ++t) acct[t] = (v4f){0.f, 0.f, 0.f, 0.f};
    #pragma unroll
    for (int k0 = 0; k0 < 128; k0 += 32) {
        v8s a = *(const v8s*)&Al[arow][k0 + quad * 8];
        #pragma unroll
        for (int t = 0; t < 8; ++t) {
            v8s b = *(const v8s*)&Wl[t * 16 + m][k0 + quad * 8];
            acct[t] = __builtin_amdgcn_mfma_f32_16x16x32_bf16(a, b, acct[t], 0, 0, 0);
        }
    }
    __syncthreads();   // all waves done reading Wl/Al

    // ---- B -> Bl (bias + deg-mask, bf16) ----
    {
        float btv[8];
        #pragma unroll
        for (int t = 0; t < 8; ++t) btv[t] = bt[t * 16 + m];
        #pragma unroll
        for (int r = 0; r < 4; ++r) {
            int n = nb + wave * 16 + quad * 4 + r;
            bool has = (n < N) && (rowptr[n + 1] > rowptr[n]);
            #pragma unroll
            for (int t = 0; t < 8; ++t) {
                float val = has ? (acct[t][r] + btv[t]) : 0.f;
                Bl[wave * 16 + quad * 4 + r][t * 16 + m] = f2bf(val);
            }
        }
    }
    // ---- restage Wl <- Wu half0, Al <- A1 ----
    #pragma unroll
    for (int i = 0; i < 8; ++i) {
        int c = i * 256 + tid;
        int row = c >> 4;
        int c8 = (c & 15) * 8;
        *(uint4*)&Wl[row][c8] = *(const uint4*)(Wu + row * 256 + c8);
    }
    #pragma unroll
    for (int i = 0; i < 4; ++i) {
        int c = i * 256 + tid;
        int row = c >> 4;
        int c8 = (c & 15) * 8;
        int n = nb + row;
        uint4 v = {0u, 0u, 0u, 0u};
        if (n < N) v = *(const uint4*)(A1 + (size_t)n * DIM + c8);
        *(uint4*)&Al[row][c8] = v;
    }
    __syncthreads();

    // ---- update MFMA half0 (A1 part) ----
    v4f accu[8];
    #pragma unroll
    for (int t = 0; t < 8; ++t) accu[t] = (v4f){0.f, 0.f, 0.f, 0.f};
    #pragma unroll
    for (int k0 = 0; k0 < 128; k0 += 32) {
        v8s a = *(const v8s*)&Al[arow][k0 + quad * 8];
        #pragma unroll
        for (int t = 0; t < 8; ++t) {
            v8s b = *(const v8s*)&Wl[t * 16 + m][k0 + quad * 8];
            accu[t] = __builtin_amdgcn_mfma_f32_16x16x32_bf16(a, b, accu[t], 0, 0, 0);
        }
    }
    __syncthreads();

    // ---- restage Wl <- Wu half1 ----
    #pragma unroll
    for (int i = 0; i < 8; ++i) {
        int c = i * 256 + tid;
        int row = c >> 4;
        int c8 = (c & 15) * 8;
        *(uint4*)&Wl[row][c8] = *(const uint4*)(Wu + row * 256 + 128 + c8);
    }
    __syncthreads();

    // ---- update MFMA half1 (B part, from Bl) ----
    #pragma unroll
    for (int k0 = 0; k0 < 128; k0 += 32) {
        v8s a = *(const v8s*)&Bl[arow][k0 + quad * 8];
        #pragma unroll
        for (int t = 0; t < 8; ++t) {
            v8s b = *(const v8s*)&Wl[t * 16 + m][k0 + quad * 8];
            accu[t] = __builtin_amdgcn_mfma_f32_16x16x32_bf16(a, b, accu[t], 0, 0, 0);
        }
    }

    // ---- epilogue ----
    float buv[8];
    #pragma unroll
    for (int t = 0; t < 8; ++t) buv[t] = bu[t * 16 + m];
    #pragma unroll
    for (int r = 0; r < 4; ++r) {
        int n = nb + wave * 16 + quad * 4 + r;
        if (n >= N) continue;
        #pragma unroll
        for (int t = 0; t < 8; ++t) {
            float val = accu[t][r] + buv[t];
            val = val > 0.f ? val : 0.f;
            if (outC) outC[(size_t)n * DIM + t * 16 + m] = f2bf(val);
            if (outF) outF[(size_t)n * DIM + t * 16 + m] = val;
        }
    }
}

extern "C" void kernel_launch(void* const* d_in, const int* in_sizes, int n_in,
                              void* d_out, int out_size, void* d_ws, size_t ws_size,
                              hipStream_t stream)
{
    const float* tile_h   = (const float*)d_in[0];
    const float* piece_h  = (const float*)d_in[1];
    const int* tile_src   = (const int*)d_in[2];
    const int* piece_dst  = (const int*)d_in[3];
    const int* piece_src  = (const int*)d_in[4];
    const int* tile_dst   = (const int*)d_in[5];
    const int* t_src      = (const int*)d_in[6];
    const int* t_dst      = (const int*)d_in[7];
    const float* b_t2p = (const float*)d_in[9];
    const float* b_pu  = (const float*)d_in[11];
    const float* b_p2t = (const float*)d_in[13];
    const float* b_tup = (const float*)d_in[15];
    const float* b_t2t = (const float*)d_in[17];
    const float* b_tut = (const float*)d_in[19];

    const int NT  = in_sizes[0] / DIM;   // 50000
    const int NP  = in_sizes[1] / DIM;   // 25000
    const int EPT = in_sizes[2];         // 400000
    const int ETT = in_sizes[6];         // 600000
    const int ET  = 2 * EPT + ETT;       // 1.4M

    // ---- workspace layout ----
    char* ws = (char*)d_ws;
    size_t off = 0;
    int* deg = (int*)(ws + off);      off += (size_t)(NP + 2 * NT) * sizeof(int);
    int* cur = (int*)(ws + off);      off += (size_t)(NP + 2 * NT) * sizeof(int);
    off = (off + 255) & ~(size_t)255;
    int* partial = (int*)(ws + off);  off += (size_t)(NP + 2 * NT) * sizeof(int);
    off = (off + 255) & ~(size_t)255;
    int* rowptr = (int*)(ws + off);   off += (size_t)(NP + 2 * NT + 3) * sizeof(int);
    off = (off + 255) & ~(size_t)255;
    int* bsum = (int*)(ws + off);     off += 128 * sizeof(int);
    off = (off + 255) & ~(size_t)255;
    int* el1 = (int*)(ws + off);      off += (size_t)EPT * sizeof(int);
    int* el2 = (int*)(ws + off);      off += (size_t)EPT * sizeof(int);
    int* el3 = (int*)(ws + off);      off += (size_t)ETT * sizeof(int);
    off = (off + 255) & ~(size_t)255;
    u16* A = (u16*)(ws + off);        off += (size_t)NT * DIM * sizeof(u16);   // meanA
    off = (off + 255) & ~(size_t)255;
    u16* C = (u16*)(ws + off);        off += (size_t)NT * DIM * sizeof(u16);   // node-mid
    off = (off + 255) & ~(size_t)255;
    u16* arena = (u16*)(ws + off);    // bf16: Th | Ph | 6 weights

    const u32 nTh = (u32)NT * DIM, nPh = (u32)NP * DIM;
    u32 pfx[9];
    pfx[0] = 0;
    pfx[1] = nTh;                  // Ph
    pfx[2] = pfx[1] + nPh;         // W_t2p
    pfx[3] = pfx[2] + 16384;       // W_pu
    pfx[4] = pfx[3] + 32768;       // W_p2t
    pfx[5] = pfx[4] + 16384;       // W_tup
    pfx[6] = pfx[5] + 32768;       // W_t2t
    pfx[7] = pfx[6] + 16384;       // W_tut
    pfx[8] = pfx[7] + 32768;       // total

    u16* Th = arena + pfx[0];
    u16* Ph = arena + pfx[1];
    const u16* Wt2p = arena + pfx[2];
    const u16* Wpu  = arena + pfx[3];
    const u16* Wp2t = arena + pfx[4];
    const u16* Wtup = arena + pfx[5];
    const u16* Wt2t = arena + pfx[6];
    const u16* Wtut = arena + pfx[7];

    int* rp1 = rowptr;
    int* rp2 = rowptr + NP + 1;
    int* rp3 = rowptr + NP + 1 + NT + 1;

    float* out_tile  = (float*)d_out;
    float* out_piece = out_tile + (size_t)NT * DIM;

    dim3 blk(256);
    const int B1 = (NP + 2047) >> 11, B2 = (NT + 2047) >> 11;
    dim3 g_scan((unsigned)(B1 + 2 * B2));
    dim3 g_edges((unsigned)((ET + 255) / 256));
    dim3 g_zdeg((unsigned)((NP + 2 * NT + 255) / 256));
    dim3 g_gp((unsigned)((NP + 7) / 8));
    dim3 g_gt((unsigned)((NT + 7) / 8));
    dim3 g_np((unsigned)((NP + 63) / 64));
    dim3 g_nt((unsigned)((NT + 63) / 64));

    // ---- conversions (1 launch) ----
    CvtArgs ca;
    ca.s[0] = tile_h; ca.s[1] = piece_h;
    ca.s[2] = (const float*)d_in[8];  ca.s[3] = (const float*)d_in[10];
    ca.s[4] = (const float*)d_in[12]; ca.s[5] = (const float*)d_in[14];
    ca.s[6] = (const float*)d_in[16]; ca.s[7] = (const float*)d_in[18];
    for (int i = 0; i < 9; ++i) ca.pfx[i] = pfx[i];
    int n8 = (int)(pfx[8] / 8);
    hipLaunchKernelGGL(cvt_all, dim3((n8 + 255) / 256), blk, 0, stream, ca, arena, n8);

    // ---- CSR builds for all 3 stages (4 launches) ----
    hipLaunchKernelGGL(zeroi_kernel, g_zdeg, blk, 0, stream, deg, NP + 2 * NT);
    hipLaunchKernelGGL(hist3, g_edges, blk, 0, stream,
                       piece_dst, tile_dst, t_dst, EPT, ETT, deg, NP, NT);
    hipLaunchKernelGGL(scan_part3, g_scan, blk, 0, stream, deg, partial, bsum, NP, NT);
    hipLaunchKernelGGL(scan_fix3, g_scan, blk, 0, stream,
                       partial, bsum, rowptr, cur, NP, NT, EPT, ETT);
    hipLaunchKernelGGL(fill3, g_edges, blk, 0, stream,
                       tile_src, piece_dst, piece_src, tile_dst, t_src, t_dst,
                       EPT, ETT, rowptr, cur, el1, el2, el3, NP, NT);

    // ---- Stage 1: tile -> piece ----
    hipLaunchKernelGGL(gather_mean_kernel, g_gp, blk, 0, stream,
                       Th, el1, rp1, NP, A);
    hipLaunchKernelGGL(stage_fused, g_np, blk, 0, stream,
                       A, rp1, Wt2p, b_t2p, Ph, Wpu, b_pu, C, out_piece, NP);

    // ---- Stage 2: piece -> tile (gather reads C = piece-mid) ----
    hipLaunchKernelGGL(gather_mean_kernel, g_gt, blk, 0, stream,
                       C, el2, rp2, NT, A);
    hipLaunchKernelGGL(stage_fused, g_nt, blk, 0, stream,
                       A, rp2, Wp2t, b_p2t, Th, Wtup, b_tup, C, (float*)nullptr, NT);

    // ---- Stage 3: tile -> tile (gather reads C = tile-mid) ----
    hipLaunchKernelGGL(gather_mean_kernel, g_gt, blk, 0, stream,
                       C, el3, rp3, NT, A);
    hipLaunchKernelGGL(stage_fused, g_nt, blk, 0, stream,
                       A, rp3, Wt2t, b_t2t, C, Wtut, b_tut, (u16*)nullptr, out_tile, NT);
}